// Round 12
// baseline (208.050 us; speedup 1.0000x reference)
//
#include <hip/hip_runtime.h>
#include <stdint.h>

#define B_ 64
#define D_ 1024
#define O_ 512
#define N_ 128
// rows = O_*D_ = 524288 weight bitstream rows, each of length N_=128

__device__ __forceinline__ uint32_t rotl32(uint32_t x, uint32_t d) {
  // v_alignbit_b32: ((x:x) >> (32-d)) == rotl(x, d) — single VALU inst.
  return __builtin_amdgcn_alignbit(x, x, 32u - d);
}

// Threefry-2x32, 20 rounds, key fixed to jax.random.key(42) -> (0, 42).
__device__ __forceinline__ void threefry2x32(uint32_t c0, uint32_t c1,
                                             uint32_t& r0, uint32_t& r1) {
  const uint32_t ks0 = 0u;
  const uint32_t ks1 = 42u;
  const uint32_t ks2 = 0u ^ 42u ^ 0x1BD11BDAu;
  uint32_t x0 = c0 + ks0;
  uint32_t x1 = c1 + ks1;
#define RND(R) { x0 += x1; x1 = rotl32(x1, R); x1 ^= x0; }
  RND(13) RND(15) RND(26) RND(6)
  x0 += ks1; x1 += ks2 + 1u;
  RND(17) RND(29) RND(16) RND(24)
  x0 += ks2; x1 += ks0 + 2u;
  RND(13) RND(15) RND(26) RND(6)
  x0 += ks0; x1 += ks1 + 3u;
  RND(17) RND(29) RND(16) RND(24)
  x0 += ks1; x1 += ks2 + 4u;
  RND(13) RND(15) RND(26) RND(6)
  x0 += ks2; x1 += ks0 + 5u;
#undef RND
  r0 = x0; r1 = x1;
}

// 32-bit random draw for flat index i, jax_threefry_partitionable semantics:
// counter = (hi32(i)=0, lo32(i)=i), output = out0 ^ out1.
__device__ __forceinline__ uint32_t rand_bits(uint32_t i) {
  uint32_t a, b;
  threefry2x32(0u, i, a, b);
  return a ^ b;
}

// K1: pack input bits along d.  xp[(b*8+g)*128 + t] is a uint4; component e,
// bit j  <->  x[b][d][t] with d = g*128 + e*32 + j.
__global__ void pack_x(const int* __restrict__ x, uint32_t* __restrict__ xp) {
  const int t   = threadIdx.x;            // 0..127
  const int idx = blockIdx.x;             // b*32 + g*4 + e
  const int b   = idx >> 5;
  const int g   = (idx >> 2) & 7;
  const int e   = idx & 3;
  const int* src = x + ((b * D_) + (g * 128 + e * 32)) * N_ + t;
  uint32_t w = 0;
#pragma unroll
  for (int j = 0; j < 32; ++j)
    w |= (uint32_t)(src[j * N_] & 1) << j;
  xp[(((b * 8) + g) * N_ + t) * 4 + e] = w;
}

// K2: per (o,d) row, reproduce the weight bitstream exactly.
// One wave per row: lane holds keys for t=lane and t=lane+64.
// key = ((rand>>2)&0xFFFFFF80) | t  (monotone in u, stable tie-break by t,
// all 128 keys distinct).  The n smallest keys get bit 1,
// n = round_half_even(clip(p,0,1)*128).
//
// Selection = the SAME verified dyadic bisection probe sequence as
// Rounds 6/9 (mid = lo + 2^30>>iter, exit when count(<mid)==n, ballots
// are the mask), but with the per-iteration bookkeeping REBALANCED:
// lo/mid live in VGPRs (v_cndmask update, v_cmp vs n), only w/counts on
// the CU-shared scalar unit.  6 VALU + 6 co-issued SALU per iter vs
// 4 VALU + 13 SALU before — the scalar pipe was the saturated resource
// (1 op/cyc/CU shared by 4 SIMDs; ~266k cyc/CU ~= 111 us).
// HARDENED TERMINATION (Round-9 proof): after 30 halvings w==0, width==1,
// invariant count(<lo) < n <= count(<lo+1) with distinct keys forces
// count(<lo+1)==n, so mask = ballot(k < lo+1).
__global__ void gen_weights(const float* __restrict__ kern, uint4* __restrict__ wtmp) {
  const int lane = threadIdx.x & 63;
  const int wave = threadIdx.x >> 6;
  const int row0 = blockIdx.x * 32 + wave * 8;
  const uint32_t lane2 = (uint32_t)lane + 64u;
  const uint32_t KMASK = 0xFFFFFF80u;
#pragma unroll
  for (int rr = 0; rr < 8; ++rr) {
    const int row = row0 + rr;
    float p = kern[row];
    p = fminf(fmaxf(p, 0.0f), 1.0f);
    const int n = (int)rintf(p * 128.0f);   // RNE, matches jnp.round; uniform

    const uint32_t i0 = (uint32_t)row * 128u + (uint32_t)lane;
    const uint32_t b0 = rand_bits(i0);
    const uint32_t b1 = rand_bits(i0 + 64u);
    const uint32_t k0 = ((b0 >> 2) & KMASK) | (uint32_t)lane;
    const uint32_t k1 = ((b1 >> 2) & KMASK) | lane2;

    uint64_t m0, m1;
    if (n <= 0) {                 // uniform condition (verified path)
      m0 = 0ull; m1 = 0ull;
    } else if (n >= 128) {
      m0 = ~0ull; m1 = ~0ull;
    } else {
      uint64_t q0, q1;
      uint32_t sw, sc, sc2, vlo, vmid;
      asm volatile(
        "v_mov_b32 %[vlo], 0\n\t"
        "s_mov_b32 %[sw], 0x40000000\n\t"          // 2^30 (keys are 30-bit)
        "Lbs%=:\n\t"
        "s_lshr_b32 %[sw], %[sw], 1\n\t"
        "v_add_u32 %[vmid], %[sw], %[vlo]\n\t"     // mid = lo + w
        "v_cmp_lt_u32 %[q0], %[k0], %[vmid]\n\t"   // ballot stream 0
        "v_cmp_lt_u32 %[q1], %[k1], %[vmid]\n\t"   // ballot stream 1
        "s_bcnt1_i32_b64 %[sc], %[q0]\n\t"
        "s_bcnt1_i32_b64 %[sc2], %[q1]\n\t"
        "s_add_i32 %[sc], %[sc], %[sc2]\n\t"
        "v_cmp_ge_u32 vcc, %[sc], %[vn]\n\t"       // c >= n ?
        "v_cndmask_b32 %[vlo], %[vmid], %[vlo], vcc\n\t" // lo = c>=n ? lo : mid
        "v_cmp_eq_u32 vcc, %[sc], %[vn]\n\t"
        "s_cbranch_vccnz Ldone%=\n\t"              // c==n: ballots are the mask
        "s_cmp_lg_u32 %[sw], 0\n\t"
        "s_cbranch_scc1 Lbs%=\n\t"
        // w==0: width==1, threshold = lo+1 exactly (see proof above)
        "v_add_u32 %[vmid], 1, %[vlo]\n\t"
        "v_cmp_lt_u32 %[q0], %[k0], %[vmid]\n\t"
        "v_cmp_lt_u32 %[q1], %[k1], %[vmid]\n\t"
        "Ldone%=:\n\t"
        : [q0] "=&s"(q0), [q1] "=&s"(q1), [sw] "=&s"(sw), [sc] "=&s"(sc),
          [sc2] "=&s"(sc2), [vlo] "=&v"(vlo), [vmid] "=&v"(vmid)
        : [k0] "v"(k0), [k1] "v"(k1), [vn] "v"(n)
        : "scc", "vcc");
      m0 = q0; m1 = q1;
    }
    if (lane == 0) {
      wtmp[row] = make_uint4((uint32_t)m0, (uint32_t)(m0 >> 32),
                             (uint32_t)m1, (uint32_t)(m1 >> 32));
    }
  }
}

// K3: transpose t-packed weight rows into d-packed words matching xp layout.
__global__ void pack_w(const uint32_t* __restrict__ wtmp, uint32_t* __restrict__ wp) {
  const int t   = threadIdx.x;            // 0..127
  const int idx = blockIdx.x;             // o*8 + g
  const int o   = idx >> 3;
  const int g   = idx & 7;
  const int word = t >> 5, bit = t & 31;
  const uint32_t* base = wtmp + (size_t)(o * D_ + g * 128) * 4 + word;
#pragma unroll
  for (int e = 0; e < 4; ++e) {
    uint32_t w = 0;
#pragma unroll
    for (int j = 0; j < 32; ++j)
      w |= ((base[(e * 32 + j) * 4] >> bit) & 1u) << j;
    wp[(((o * 8) + g) * N_ + t) * 4 + e] = w;
  }
}

// K4: out[b][o][t] = popc-dot over 1024 d's (32 words) / 128.  Exact ints.
__global__ void popc_gemm(const uint4* __restrict__ wp, const uint4* __restrict__ xp,
                          float* __restrict__ out) {
  const int t     = threadIdx.x & 127;
  const int oi    = threadIdx.x >> 7;
  const int opair = blockIdx.x >> 3;
  const int btile = blockIdx.x & 7;
  const int o     = opair * 2 + oi;

  uint4 w[8];
#pragma unroll
  for (int g = 0; g < 8; ++g) w[g] = wp[(o * 8 + g) * N_ + t];

#pragma unroll
  for (int ib = 0; ib < 8; ++ib) {
    const int b = btile * 8 + ib;
    uint32_t acc = 0;
#pragma unroll
    for (int g = 0; g < 8; ++g) {
      const uint4 xv = xp[(b * 8 + g) * N_ + t];
      acc += __popc(w[g].x & xv.x);
      acc += __popc(w[g].y & xv.y);
      acc += __popc(w[g].z & xv.z);
      acc += __popc(w[g].w & xv.w);
    }
    out[((size_t)(b * O_) + o) * N_ + t] = (float)acc * (1.0f / 128.0f);
  }
}

extern "C" void kernel_launch(void* const* d_in, const int* in_sizes, int n_in,
                              void* d_out, int out_size, void* d_ws, size_t ws_size,
                              hipStream_t stream) {
  const int*   x    = (const int*)d_in[0];     // (64,1024,128) int32 0/1
  const float* kern = (const float*)d_in[1];   // (512,1024) float32
  float*       out  = (float*)d_out;           // (64,512,128) float32

  char* ws = (char*)d_ws;
  uint32_t* xp   = (uint32_t*)ws;                    // 1 MB
  uint4*    wtmp = (uint4*)(ws + (1u << 20));        // 8 MB
  uint32_t* wp   = (uint32_t*)(ws + (9u << 20));     // 8 MB

  hipLaunchKernelGGL(pack_x,      dim3(2048),  dim3(128), 0, stream, x, xp);
  hipLaunchKernelGGL(gen_weights, dim3(16384), dim3(256), 0, stream, kern, wtmp);
  hipLaunchKernelGGL(pack_w,      dim3(4096),  dim3(128), 0, stream,
                     (const uint32_t*)wtmp, wp);
  hipLaunchKernelGGL(popc_gemm,   dim3(2048),  dim3(256), 0, stream,
                     (const uint4*)wp, (const uint4*)xp, out);
}

// Round 13
// 196.493 us; speedup vs baseline: 1.0588x; 1.0588x over previous
//
#include <hip/hip_runtime.h>
#include <stdint.h>

#define B_ 64
#define D_ 1024
#define O_ 512
#define N_ 128
// rows = O_*D_ = 524288 weight bitstream rows, each of length N_=128

__device__ __forceinline__ uint32_t rotl32(uint32_t x, uint32_t d) {
  // v_alignbit_b32: ((x:x) >> (32-d)) == rotl(x, d) — single VALU inst.
  return __builtin_amdgcn_alignbit(x, x, 32u - d);
}

// Threefry-2x32, 20 rounds, key fixed to jax.random.key(42) -> (0, 42).
__device__ __forceinline__ void threefry2x32(uint32_t c0, uint32_t c1,
                                             uint32_t& r0, uint32_t& r1) {
  const uint32_t ks0 = 0u;
  const uint32_t ks1 = 42u;
  const uint32_t ks2 = 0u ^ 42u ^ 0x1BD11BDAu;
  uint32_t x0 = c0 + ks0;
  uint32_t x1 = c1 + ks1;
#define RND(R) { x0 += x1; x1 = rotl32(x1, R); x1 ^= x0; }
  RND(13) RND(15) RND(26) RND(6)
  x0 += ks1; x1 += ks2 + 1u;
  RND(17) RND(29) RND(16) RND(24)
  x0 += ks2; x1 += ks0 + 2u;
  RND(13) RND(15) RND(26) RND(6)
  x0 += ks0; x1 += ks1 + 3u;
  RND(17) RND(29) RND(16) RND(24)
  x0 += ks1; x1 += ks2 + 4u;
  RND(13) RND(15) RND(26) RND(6)
  x0 += ks2; x1 += ks0 + 5u;
#undef RND
  r0 = x0; r1 = x1;
}

// 32-bit random draw for flat index i, jax_threefry_partitionable semantics:
// counter = (hi32(i)=0, lo32(i)=i), output = out0 ^ out1.
__device__ __forceinline__ uint32_t rand_bits(uint32_t i) {
  uint32_t a, b;
  threefry2x32(0u, i, a, b);
  return a ^ b;
}

// K1: pack input bits along d.  xp[(b*8+g)*128 + t] is a uint4; component e,
// bit j  <->  x[b][d][t] with d = g*128 + e*32 + j.
__global__ void pack_x(const int* __restrict__ x, uint32_t* __restrict__ xp) {
  const int t   = threadIdx.x;            // 0..127
  const int idx = blockIdx.x;             // b*32 + g*4 + e
  const int b   = idx >> 5;
  const int g   = (idx >> 2) & 7;
  const int e   = idx & 3;
  const int* src = x + ((b * D_) + (g * 128 + e * 32)) * N_ + t;
  uint32_t w = 0;
#pragma unroll
  for (int j = 0; j < 32; ++j)
    w |= (uint32_t)(src[j * N_] & 1) << j;
  xp[(((b * 8) + g) * N_ + t) * 4 + e] = w;
}

// K2: per (o,d) row, reproduce the weight bitstream exactly.
// One wave per row: lane holds keys for t=lane and t=lane+64.
// key = ((rand>>2)&0xFFFFFF80) | t  (monotone in u, stable tie-break by t,
// all 128 keys distinct).  The n smallest keys get bit 1,
// n = round_half_even(clip(p,0,1)*128).
//
// Selection = the twice-verified R6/R9 (lo,hi) bisection in inline asm with
// hardened width-1 termination (count(<lo) < n <= count(<hi) + distinct
// keys => count(<hi)==n, mask = ballot(k < hi)).  The asm block is
// byte-identical to Round 9's.
//
// SOFTWARE PIPELINE (this round's change): row rr+1's threefry keys and n
// are computed BEFORE row rr's select asm.  Round-12 counters showed
// VGPR_Count=8 — the compiler squeezed the whole row into 8 registers and
// pays ~2x dynamic VALU in mov/recompute churn (implied ~300 VALU/row vs
// ~170 static).  Pipelining forces the next row's state live across the
// asm (more registers, zero occupancy cost: 2048-thread/CU cap dominates)
// and gives the scheduler independent VALU work around each asm block.
__global__ void gen_weights(const float* __restrict__ kern, uint4* __restrict__ wtmp) {
  const int lane = threadIdx.x & 63;
  const int wave = threadIdx.x >> 6;
  const int row0 = blockIdx.x * 32 + wave * 8;
  const uint32_t lane2 = (uint32_t)lane + 64u;
  const uint32_t KMASK = 0xFFFFFF80u;
  const uint32_t base_i = (uint32_t)row0 * 128u + (uint32_t)lane;

  // prologue: keys + n for row 0
  uint32_t k0 = ((rand_bits(base_i) >> 2) & KMASK) | (uint32_t)lane;
  uint32_t k1 = ((rand_bits(base_i + 64u) >> 2) & KMASK) | lane2;
  float p0 = fminf(fmaxf(kern[row0], 0.0f), 1.0f);
  int n = (int)rintf(p0 * 128.0f);        // RNE, matches jnp.round; uniform

#pragma unroll
  for (int rr = 0; rr < 8; ++rr) {
    // issue next row's independent work first (fills VALU around the asm)
    uint32_t k0n = 0, k1n = 0; int nn = 0;
    if (rr < 7) {
      const uint32_t i0 = base_i + (uint32_t)((rr + 1) * 128);
      k0n = ((rand_bits(i0) >> 2) & KMASK) | (uint32_t)lane;
      k1n = ((rand_bits(i0 + 64u) >> 2) & KMASK) | lane2;
      float p = fminf(fmaxf(kern[row0 + rr + 1], 0.0f), 1.0f);
      nn = (int)rintf(p * 128.0f);
    }

    uint64_t m0, m1;
    if (n <= 0) {                 // uniform condition (verified path)
      m0 = 0ull; m1 = 0ull;
    } else if (n >= 128) {
      m0 = ~0ull; m1 = ~0ull;
    } else {
      uint64_t q0, q1;
      uint32_t lo, hi, mid, c, c2, ns;
      asm volatile(
        "v_readfirstlane_b32 %[ns], %[nv]\n\t"   // n -> SGPR, guaranteed
        "s_mov_b32 %[lo], 0\n\t"
        "s_mov_b32 %[hi], 0x40000000\n\t"        // 2^30 (keys are 30-bit)
        "Lbs%=:\n\t"
        "s_add_u32 %[mid], %[lo], %[hi]\n\t"
        "s_lshr_b32 %[mid], %[mid], 1\n\t"
        "v_cmp_lt_u32 %[q0], %[k0], %[mid]\n\t"  // ballot stream 0
        "v_cmp_lt_u32 %[q1], %[k1], %[mid]\n\t"  // ballot stream 1
        "s_bcnt1_i32_b64 %[c], %[q0]\n\t"
        "s_bcnt1_i32_b64 %[c2], %[q1]\n\t"
        "s_add_i32 %[c], %[c], %[c2]\n\t"
        "s_cmp_ge_i32 %[c], %[ns]\n\t"
        "s_cselect_b32 %[hi], %[mid], %[hi]\n\t" // cnt>=n ? hi=mid : lo=mid
        "s_cselect_b32 %[lo], %[lo], %[mid]\n\t"
        "s_cmp_eq_i32 %[c], %[ns]\n\t"
        "s_cbranch_scc1 Ldone%=\n\t"             // found: ballots are the mask
        "s_sub_u32 %[c2], %[hi], %[lo]\n\t"      // width
        "s_cmp_gt_u32 %[c2], 1\n\t"
        "s_cbranch_scc1 Lbs%=\n\t"
        // width==1: count(<lo) < n <= count(<hi), keys distinct
        //   => count(<hi) == n exactly.  mask = ballot(k < hi).
        "v_cmp_lt_u32 %[q0], %[k0], %[hi]\n\t"
        "v_cmp_lt_u32 %[q1], %[k1], %[hi]\n\t"
        "Ldone%=:\n\t"
        : [q0] "=&s"(q0), [q1] "=&s"(q1), [lo] "=&s"(lo), [hi] "=&s"(hi),
          [mid] "=&s"(mid), [c] "=&s"(c), [c2] "=&s"(c2), [ns] "=&s"(ns)
        : [k0] "v"(k0), [k1] "v"(k1), [nv] "v"(n)
        : "scc");
      m0 = q0; m1 = q1;
    }
    if (lane == 0) {
      wtmp[row0 + rr] = make_uint4((uint32_t)m0, (uint32_t)(m0 >> 32),
                                   (uint32_t)m1, (uint32_t)(m1 >> 32));
    }
    k0 = k0n; k1 = k1n; n = nn;
  }
}

// K3: transpose t-packed weight rows into d-packed words matching xp layout.
__global__ void pack_w(const uint32_t* __restrict__ wtmp, uint32_t* __restrict__ wp) {
  const int t   = threadIdx.x;            // 0..127
  const int idx = blockIdx.x;             // o*8 + g
  const int o   = idx >> 3;
  const int g   = idx & 7;
  const int word = t >> 5, bit = t & 31;
  const uint32_t* base = wtmp + (size_t)(o * D_ + g * 128) * 4 + word;
#pragma unroll
  for (int e = 0; e < 4; ++e) {
    uint32_t w = 0;
#pragma unroll
    for (int j = 0; j < 32; ++j)
      w |= ((base[(e * 32 + j) * 4] >> bit) & 1u) << j;
    wp[(((o * 8) + g) * N_ + t) * 4 + e] = w;
  }
}

// K4: out[b][o][t] = popc-dot over 1024 d's (32 words) / 128.  Exact ints.
__global__ void popc_gemm(const uint4* __restrict__ wp, const uint4* __restrict__ xp,
                          float* __restrict__ out) {
  const int t     = threadIdx.x & 127;
  const int oi    = threadIdx.x >> 7;
  const int opair = blockIdx.x >> 3;
  const int btile = blockIdx.x & 7;
  const int o     = opair * 2 + oi;

  uint4 w[8];
#pragma unroll
  for (int g = 0; g < 8; ++g) w[g] = wp[(o * 8 + g) * N_ + t];

#pragma unroll
  for (int ib = 0; ib < 8; ++ib) {
    const int b = btile * 8 + ib;
    uint32_t acc = 0;
#pragma unroll
    for (int g = 0; g < 8; ++g) {
      const uint4 xv = xp[(b * 8 + g) * N_ + t];
      acc += __popc(w[g].x & xv.x);
      acc += __popc(w[g].y & xv.y);
      acc += __popc(w[g].z & xv.z);
      acc += __popc(w[g].w & xv.w);
    }
    out[((size_t)(b * O_) + o) * N_ + t] = (float)acc * (1.0f / 128.0f);
  }
}

extern "C" void kernel_launch(void* const* d_in, const int* in_sizes, int n_in,
                              void* d_out, int out_size, void* d_ws, size_t ws_size,
                              hipStream_t stream) {
  const int*   x    = (const int*)d_in[0];     // (64,1024,128) int32 0/1
  const float* kern = (const float*)d_in[1];   // (512,1024) float32
  float*       out  = (float*)d_out;           // (64,512,128) float32

  char* ws = (char*)d_ws;
  uint32_t* xp   = (uint32_t*)ws;                    // 1 MB
  uint4*    wtmp = (uint4*)(ws + (1u << 20));        // 8 MB
  uint32_t* wp   = (uint32_t*)(ws + (9u << 20));     // 8 MB

  hipLaunchKernelGGL(pack_x,      dim3(2048),  dim3(128), 0, stream, x, xp);
  hipLaunchKernelGGL(gen_weights, dim3(16384), dim3(256), 0, stream, kern, wtmp);
  hipLaunchKernelGGL(pack_w,      dim3(4096),  dim3(128), 0, stream,
                     (const uint32_t*)wtmp, wp);
  hipLaunchKernelGGL(popc_gemm,   dim3(2048),  dim3(256), 0, stream,
                     (const uint4*)wp, (const uint4*)xp, out);
}

// Round 14
// 185.410 us; speedup vs baseline: 1.1221x; 1.0598x over previous
//
#include <hip/hip_runtime.h>
#include <stdint.h>

#define B_ 64
#define D_ 1024
#define O_ 512
#define N_ 128
// rows = O_*D_ = 524288 weight bitstream rows, each of length N_=128

__device__ __forceinline__ uint32_t rotl32(uint32_t x, uint32_t d) {
  // v_alignbit_b32: ((x:x) >> (32-d)) == rotl(x, d) — single VALU inst.
  return __builtin_amdgcn_alignbit(x, x, 32u - d);
}

// Threefry-2x32, 20 rounds, key fixed to jax.random.key(42) -> (0, 42).
__device__ __forceinline__ void threefry2x32(uint32_t c0, uint32_t c1,
                                             uint32_t& r0, uint32_t& r1) {
  const uint32_t ks0 = 0u;
  const uint32_t ks1 = 42u;
  const uint32_t ks2 = 0u ^ 42u ^ 0x1BD11BDAu;
  uint32_t x0 = c0 + ks0;
  uint32_t x1 = c1 + ks1;
#define RND(R) { x0 += x1; x1 = rotl32(x1, R); x1 ^= x0; }
  RND(13) RND(15) RND(26) RND(6)
  x0 += ks1; x1 += ks2 + 1u;
  RND(17) RND(29) RND(16) RND(24)
  x0 += ks2; x1 += ks0 + 2u;
  RND(13) RND(15) RND(26) RND(6)
  x0 += ks0; x1 += ks1 + 3u;
  RND(17) RND(29) RND(16) RND(24)
  x0 += ks1; x1 += ks2 + 4u;
  RND(13) RND(15) RND(26) RND(6)
  x0 += ks2; x1 += ks0 + 5u;
#undef RND
  r0 = x0; r1 = x1;
}

// 32-bit random draw for flat index i, jax_threefry_partitionable semantics:
// counter = (hi32(i)=0, lo32(i)=i), output = out0 ^ out1.
__device__ __forceinline__ uint32_t rand_bits(uint32_t i) {
  uint32_t a, b;
  threefry2x32(0u, i, a, b);
  return a ^ b;
}

// K1: pack input bits along d.  xp[(b*8+g)*128 + t] is a uint4; component e,
// bit j  <->  x[b][d][t] with d = g*128 + e*32 + j.
__global__ void pack_x(const int* __restrict__ x, uint32_t* __restrict__ xp) {
  const int t   = threadIdx.x;            // 0..127
  const int idx = blockIdx.x;             // b*32 + g*4 + e
  const int b   = idx >> 5;
  const int g   = (idx >> 2) & 7;
  const int e   = idx & 3;
  const int* src = x + ((b * D_) + (g * 128 + e * 32)) * N_ + t;
  uint32_t w = 0;
#pragma unroll
  for (int j = 0; j < 32; ++j)
    w |= (uint32_t)(src[j * N_] & 1) << j;
  xp[(((b * 8) + g) * N_ + t) * 4 + e] = w;
}

// K2: per (o,d) row, reproduce the weight bitstream exactly.
// One wave per row: lane holds keys for t=lane and t=lane+64.
// key = ((rand>>2)&0xFFFFFF80) | t  (monotone in u, stable tie-break by t,
// all 128 keys distinct).  The n smallest keys get bit 1,
// n = round_half_even(clip(p,0,1)*128).
//
// Selection: INTERPOLATION SEARCH + bisection fallback, exact by
// construction.  Keys are uniform, so K_n ~= n<<23; probe there, then
// correct by (n - count)<<23, 3 interp probes total, each clamped to the
// strict interior [lo+1, hi-1] of the invariant bracket
// (count(<lo) < n <= count(<hi)); then verified bisection.  Exit ONLY on
// count(<m)==n — any such m yields THE unique n-smallest mask.
// Termination: interp probes are strictly interior (width shrinks);
// bisection mid = max((lo+hi)>>1, lo+1) degenerates to hi at width 1,
// where distinct keys force count(<hi)==n (width-1 theorem) -> exit.
// The min-then-max clamp order auto-forces m=hi at width 1 too.
// E[probes] ~4.5 vs 9.3 for blind bisection — halves the
// v_cmp->s_bcnt->s_cselect round-trip stalls that dominate (R9/R12/R13
// all match a "VALU+SALU serialize" sum model).
__global__ void gen_weights(const float* __restrict__ kern, uint4* __restrict__ wtmp) {
  const int lane = threadIdx.x & 63;
  const int wave = threadIdx.x >> 6;
  const int row0 = blockIdx.x * 32 + wave * 8;
  const uint32_t lane2 = (uint32_t)lane + 64u;
  const uint32_t KMASK = 0xFFFFFF80u;
  const uint32_t base_i = (uint32_t)row0 * 128u + (uint32_t)lane;

  // prologue: keys + n for row 0 (R13 software pipeline kept)
  uint32_t k0 = ((rand_bits(base_i) >> 2) & KMASK) | (uint32_t)lane;
  uint32_t k1 = ((rand_bits(base_i + 64u) >> 2) & KMASK) | lane2;
  float p0 = fminf(fmaxf(kern[row0], 0.0f), 1.0f);
  int n = (int)rintf(p0 * 128.0f);        // RNE, matches jnp.round; uniform

#define PROBE_UPDATE_EXIT                                          \
      "v_cmp_lt_u32 %[q0], %[k0], %[m]\n\t"                        \
      "v_cmp_lt_u32 %[q1], %[k1], %[m]\n\t"                        \
      "s_bcnt1_i32_b64 %[c], %[q0]\n\t"                            \
      "s_bcnt1_i32_b64 %[c2], %[q1]\n\t"                           \
      "s_add_i32 %[c], %[c], %[c2]\n\t"                            \
      "s_cmp_ge_i32 %[c], %[ns]\n\t"                               \
      "s_cselect_b32 %[hi], %[m], %[hi]\n\t"                       \
      "s_cselect_b32 %[lo], %[lo], %[m]\n\t"                       \
      "s_cmp_eq_i32 %[c], %[ns]\n\t"                               \
      "s_cbranch_scc1 Ldone%=\n\t"
#define INTERP_MID                                                 \
      "s_sub_i32 %[d], %[ns], %[c]\n\t"                            \
      "s_lshl_b32 %[d], %[d], 23\n\t"                              \
      "s_add_u32 %[m], %[m], %[d]\n\t"                             \
      "s_add_u32 %[t1], %[lo], 1\n\t"                              \
      "s_add_u32 %[t2], %[hi], -1\n\t"                             \
      "s_min_u32 %[m], %[m], %[t2]\n\t"                            \
      "s_max_u32 %[m], %[m], %[t1]\n\t"

#pragma unroll
  for (int rr = 0; rr < 8; ++rr) {
    // issue next row's independent work first (fills VALU around the asm)
    uint32_t k0n = 0, k1n = 0; int nn = 0;
    if (rr < 7) {
      const uint32_t i0 = base_i + (uint32_t)((rr + 1) * 128);
      k0n = ((rand_bits(i0) >> 2) & KMASK) | (uint32_t)lane;
      k1n = ((rand_bits(i0 + 64u) >> 2) & KMASK) | lane2;
      float p = fminf(fmaxf(kern[row0 + rr + 1], 0.0f), 1.0f);
      nn = (int)rintf(p * 128.0f);
    }

    uint64_t m0, m1;
    if (n <= 0) {                 // uniform condition (verified path)
      m0 = 0ull; m1 = 0ull;
    } else if (n >= 128) {
      m0 = ~0ull; m1 = ~0ull;
    } else {
      uint64_t q0, q1;
      uint32_t lo, hi, m, c, c2, ns, d, t1, t2;
      asm volatile(
        "v_readfirstlane_b32 %[ns], %[nv]\n\t"   // n -> SGPR, guaranteed
        "s_mov_b32 %[lo], 0\n\t"
        "s_mov_b32 %[hi], 0x40000000\n\t"        // 2^30 (keys are 30-bit)
        // ---- interp probe 1: m = n<<23 (interior for n in [1,127]) ----
        "s_lshl_b32 %[m], %[ns], 23\n\t"
        PROBE_UPDATE_EXIT
        // ---- interp probe 2 ----
        INTERP_MID
        PROBE_UPDATE_EXIT
        // ---- interp probe 3 ----
        INTERP_MID
        PROBE_UPDATE_EXIT
        // ---- verified bisection, width-1 -> m=hi exact exit ----
        "Lbs%=:\n\t"
        "s_add_u32 %[m], %[lo], %[hi]\n\t"
        "s_lshr_b32 %[m], %[m], 1\n\t"
        "s_add_u32 %[t1], %[lo], 1\n\t"
        "s_max_u32 %[m], %[m], %[t1]\n\t"
        "v_cmp_lt_u32 %[q0], %[k0], %[m]\n\t"
        "v_cmp_lt_u32 %[q1], %[k1], %[m]\n\t"
        "s_bcnt1_i32_b64 %[c], %[q0]\n\t"
        "s_bcnt1_i32_b64 %[c2], %[q1]\n\t"
        "s_add_i32 %[c], %[c], %[c2]\n\t"
        "s_cmp_ge_i32 %[c], %[ns]\n\t"
        "s_cselect_b32 %[hi], %[m], %[hi]\n\t"
        "s_cselect_b32 %[lo], %[lo], %[m]\n\t"
        "s_cmp_lg_i32 %[c], %[ns]\n\t"
        "s_cbranch_scc1 Lbs%=\n\t"
        "Ldone%=:\n\t"
        : [q0] "=&s"(q0), [q1] "=&s"(q1), [lo] "=&s"(lo), [hi] "=&s"(hi),
          [m] "=&s"(m), [c] "=&s"(c), [c2] "=&s"(c2), [ns] "=&s"(ns),
          [d] "=&s"(d), [t1] "=&s"(t1), [t2] "=&s"(t2)
        : [k0] "v"(k0), [k1] "v"(k1), [nv] "v"(n)
        : "scc");
      m0 = q0; m1 = q1;
    }
    if (lane == 0) {
      wtmp[row0 + rr] = make_uint4((uint32_t)m0, (uint32_t)(m0 >> 32),
                                   (uint32_t)m1, (uint32_t)(m1 >> 32));
    }
    k0 = k0n; k1 = k1n; n = nn;
  }
#undef PROBE_UPDATE_EXIT
#undef INTERP_MID
}

// K3: transpose t-packed weight rows into d-packed words matching xp layout.
__global__ void pack_w(const uint32_t* __restrict__ wtmp, uint32_t* __restrict__ wp) {
  const int t   = threadIdx.x;            // 0..127
  const int idx = blockIdx.x;             // o*8 + g
  const int o   = idx >> 3;
  const int g   = idx & 7;
  const int word = t >> 5, bit = t & 31;
  const uint32_t* base = wtmp + (size_t)(o * D_ + g * 128) * 4 + word;
#pragma unroll
  for (int e = 0; e < 4; ++e) {
    uint32_t w = 0;
#pragma unroll
    for (int j = 0; j < 32; ++j)
      w |= ((base[(e * 32 + j) * 4] >> bit) & 1u) << j;
    wp[(((o * 8) + g) * N_ + t) * 4 + e] = w;
  }
}

// K4: out[b][o][t] = popc-dot over 1024 d's (32 words) / 128.  Exact ints.
__global__ void popc_gemm(const uint4* __restrict__ wp, const uint4* __restrict__ xp,
                          float* __restrict__ out) {
  const int t     = threadIdx.x & 127;
  const int oi    = threadIdx.x >> 7;
  const int opair = blockIdx.x >> 3;
  const int btile = blockIdx.x & 7;
  const int o     = opair * 2 + oi;

  uint4 w[8];
#pragma unroll
  for (int g = 0; g < 8; ++g) w[g] = wp[(o * 8 + g) * N_ + t];

#pragma unroll
  for (int ib = 0; ib < 8; ++ib) {
    const int b = btile * 8 + ib;
    uint32_t acc = 0;
#pragma unroll
    for (int g = 0; g < 8; ++g) {
      const uint4 xv = xp[(b * 8 + g) * N_ + t];
      acc += __popc(w[g].x & xv.x);
      acc += __popc(w[g].y & xv.y);
      acc += __popc(w[g].z & xv.z);
      acc += __popc(w[g].w & xv.w);
    }
    out[((size_t)(b * O_) + o) * N_ + t] = (float)acc * (1.0f / 128.0f);
  }
}

extern "C" void kernel_launch(void* const* d_in, const int* in_sizes, int n_in,
                              void* d_out, int out_size, void* d_ws, size_t ws_size,
                              hipStream_t stream) {
  const int*   x    = (const int*)d_in[0];     // (64,1024,128) int32 0/1
  const float* kern = (const float*)d_in[1];   // (512,1024) float32
  float*       out  = (float*)d_out;           // (64,512,128) float32

  char* ws = (char*)d_ws;
  uint32_t* xp   = (uint32_t*)ws;                    // 1 MB
  uint4*    wtmp = (uint4*)(ws + (1u << 20));        // 8 MB
  uint32_t* wp   = (uint32_t*)(ws + (9u << 20));     // 8 MB

  hipLaunchKernelGGL(pack_x,      dim3(2048),  dim3(128), 0, stream, x, xp);
  hipLaunchKernelGGL(gen_weights, dim3(16384), dim3(256), 0, stream, kern, wtmp);
  hipLaunchKernelGGL(pack_w,      dim3(4096),  dim3(128), 0, stream,
                     (const uint32_t*)wtmp, wp);
  hipLaunchKernelGGL(popc_gemm,   dim3(2048),  dim3(256), 0, stream,
                     (const uint4*)wp, (const uint4*)xp, out);
}

// Round 15
// 176.301 us; speedup vs baseline: 1.1801x; 1.0517x over previous
//
#include <hip/hip_runtime.h>
#include <stdint.h>

#define B_ 64
#define D_ 1024
#define O_ 512
#define N_ 128
// rows = O_*D_ = 524288 weight bitstream rows, each of length N_=128

__device__ __forceinline__ uint32_t rotl32(uint32_t x, uint32_t d) {
  // v_alignbit_b32: ((x:x) >> (32-d)) == rotl(x, d) — single VALU inst.
  return __builtin_amdgcn_alignbit(x, x, 32u - d);
}

// Threefry-2x32, 20 rounds, key fixed to jax.random.key(42) -> (0, 42).
__device__ __forceinline__ void threefry2x32(uint32_t c0, uint32_t c1,
                                             uint32_t& r0, uint32_t& r1) {
  const uint32_t ks0 = 0u;
  const uint32_t ks1 = 42u;
  const uint32_t ks2 = 0u ^ 42u ^ 0x1BD11BDAu;
  uint32_t x0 = c0 + ks0;
  uint32_t x1 = c1 + ks1;
#define RND(R) { x0 += x1; x1 = rotl32(x1, R); x1 ^= x0; }
  RND(13) RND(15) RND(26) RND(6)
  x0 += ks1; x1 += ks2 + 1u;
  RND(17) RND(29) RND(16) RND(24)
  x0 += ks2; x1 += ks0 + 2u;
  RND(13) RND(15) RND(26) RND(6)
  x0 += ks0; x1 += ks1 + 3u;
  RND(17) RND(29) RND(16) RND(24)
  x0 += ks1; x1 += ks2 + 4u;
  RND(13) RND(15) RND(26) RND(6)
  x0 += ks2; x1 += ks0 + 5u;
#undef RND
  r0 = x0; r1 = x1;
}

// 32-bit random draw for flat index i, jax_threefry_partitionable semantics:
// counter = (hi32(i)=0, lo32(i)=i), output = out0 ^ out1.
__device__ __forceinline__ uint32_t rand_bits(uint32_t i) {
  uint32_t a, b;
  threefry2x32(0u, i, a, b);
  return a ^ b;
}

// K1: pack input bits along d.  xp[(b*8+g)*128 + t] is a uint4; component e,
// bit j  <->  x[b][d][t] with d = g*128 + e*32 + j.
__global__ void pack_x(const int* __restrict__ x, uint32_t* __restrict__ xp) {
  const int t   = threadIdx.x;            // 0..127
  const int idx = blockIdx.x;             // b*32 + g*4 + e
  const int b   = idx >> 5;
  const int g   = (idx >> 2) & 7;
  const int e   = idx & 3;
  const int* src = x + ((b * D_) + (g * 128 + e * 32)) * N_ + t;
  uint32_t w = 0;
#pragma unroll
  for (int j = 0; j < 32; ++j)
    w |= (uint32_t)(src[j * N_] & 1) << j;
  xp[(((b * 8) + g) * N_ + t) * 4 + e] = w;
}

// K2 (FUSED gen_weights + pack_w): per (o,d) row, reproduce the weight
// bitstream exactly, then transpose in-block to the d-packed GEMM layout.
//
// Row->mask: lane holds keys for t=lane and t=lane+64.
// key = ((rand>>2)&0xFFFFFF80) | t  (monotone in u, stable tie-break by t,
// all 128 keys distinct).  The n smallest keys get bit 1,
// n = round_half_even(clip(p,0,1)*128).
// Selection: interpolation search (4 probes) + verified bisection fallback;
// exit ONLY on count(<m)==n (unique mask); width-1 theorem guarantees
// termination (R9/R14 verified; asm macros byte-identical to R14 + one
// extra interp probe).
//
// Fusion layout math: block = 32 consecutive rows = one o (row/1024 const),
// 32 consecutive d's [d0, d0+32), d0 = (blk%32)*32 -> one (g,e) word-column:
// o = blk>>5, g = (blk>>2)&7, e = blk&3.  Each row's 4 mask words go to
// LDS; after a barrier, 256 threads bit-transpose: thread (p=tid>>7,
// t=tid&127) gathers rows p*16..p*16+15 bit t, halves merged via LDS, and
// wp word (o,g,e,t) stored t-contiguous (coalesced).
// wp layout: wp[((o*8+g)*4 + e)*128 + t].
__global__ void gen_weights(const float* __restrict__ kern, uint32_t* __restrict__ wp) {
  __shared__ uint32_t lds_m[32][4];
  __shared__ uint32_t lds_p[2][128];

  const int lane = threadIdx.x & 63;
  const int wave = threadIdx.x >> 6;
  const int row0 = blockIdx.x * 32 + wave * 8;
  const uint32_t lane2 = (uint32_t)lane + 64u;
  const uint32_t KMASK = 0xFFFFFF80u;
  const uint32_t base_i = (uint32_t)row0 * 128u + (uint32_t)lane;

  // prologue: keys + n for row 0 (software pipeline)
  uint32_t k0 = ((rand_bits(base_i) >> 2) & KMASK) | (uint32_t)lane;
  uint32_t k1 = ((rand_bits(base_i + 64u) >> 2) & KMASK) | lane2;
  float p0 = fminf(fmaxf(kern[row0], 0.0f), 1.0f);
  int n = (int)rintf(p0 * 128.0f);        // RNE, matches jnp.round; uniform

#define PROBE_UPDATE_EXIT                                          \
      "v_cmp_lt_u32 %[q0], %[k0], %[m]\n\t"                        \
      "v_cmp_lt_u32 %[q1], %[k1], %[m]\n\t"                        \
      "s_bcnt1_i32_b64 %[c], %[q0]\n\t"                            \
      "s_bcnt1_i32_b64 %[c2], %[q1]\n\t"                           \
      "s_add_i32 %[c], %[c], %[c2]\n\t"                            \
      "s_cmp_ge_i32 %[c], %[ns]\n\t"                               \
      "s_cselect_b32 %[hi], %[m], %[hi]\n\t"                       \
      "s_cselect_b32 %[lo], %[lo], %[m]\n\t"                       \
      "s_cmp_eq_i32 %[c], %[ns]\n\t"                               \
      "s_cbranch_scc1 Ldone%=\n\t"
#define INTERP_MID                                                 \
      "s_sub_i32 %[d], %[ns], %[c]\n\t"                            \
      "s_lshl_b32 %[d], %[d], 23\n\t"                              \
      "s_add_u32 %[m], %[m], %[d]\n\t"                             \
      "s_add_u32 %[t1], %[lo], 1\n\t"                              \
      "s_add_u32 %[t2], %[hi], -1\n\t"                             \
      "s_min_u32 %[m], %[m], %[t2]\n\t"                            \
      "s_max_u32 %[m], %[m], %[t1]\n\t"

#pragma unroll
  for (int rr = 0; rr < 8; ++rr) {
    // issue next row's independent work first (fills VALU around the asm)
    uint32_t k0n = 0, k1n = 0; int nn = 0;
    if (rr < 7) {
      const uint32_t i0 = base_i + (uint32_t)((rr + 1) * 128);
      k0n = ((rand_bits(i0) >> 2) & KMASK) | (uint32_t)lane;
      k1n = ((rand_bits(i0 + 64u) >> 2) & KMASK) | lane2;
      float p = fminf(fmaxf(kern[row0 + rr + 1], 0.0f), 1.0f);
      nn = (int)rintf(p * 128.0f);
    }

    uint64_t m0, m1;
    if (n <= 0) {                 // uniform condition (verified path)
      m0 = 0ull; m1 = 0ull;
    } else if (n >= 128) {
      m0 = ~0ull; m1 = ~0ull;
    } else {
      uint64_t q0, q1;
      uint32_t lo, hi, m, c, c2, ns, d, t1, t2;
      asm volatile(
        "v_readfirstlane_b32 %[ns], %[nv]\n\t"   // n -> SGPR, guaranteed
        "s_mov_b32 %[lo], 0\n\t"
        "s_mov_b32 %[hi], 0x40000000\n\t"        // 2^30 (keys are 30-bit)
        // ---- interp probe 1: m = n<<23 (interior for n in [1,127]) ----
        "s_lshl_b32 %[m], %[ns], 23\n\t"
        PROBE_UPDATE_EXIT
        // ---- interp probe 2 ----
        INTERP_MID
        PROBE_UPDATE_EXIT
        // ---- interp probe 3 ----
        INTERP_MID
        PROBE_UPDATE_EXIT
        // ---- interp probe 4 ----
        INTERP_MID
        PROBE_UPDATE_EXIT
        // ---- verified bisection, width-1 -> m=hi exact exit ----
        "Lbs%=:\n\t"
        "s_add_u32 %[m], %[lo], %[hi]\n\t"
        "s_lshr_b32 %[m], %[m], 1\n\t"
        "s_add_u32 %[t1], %[lo], 1\n\t"
        "s_max_u32 %[m], %[m], %[t1]\n\t"
        "v_cmp_lt_u32 %[q0], %[k0], %[m]\n\t"
        "v_cmp_lt_u32 %[q1], %[k1], %[m]\n\t"
        "s_bcnt1_i32_b64 %[c], %[q0]\n\t"
        "s_bcnt1_i32_b64 %[c2], %[q1]\n\t"
        "s_add_i32 %[c], %[c], %[c2]\n\t"
        "s_cmp_ge_i32 %[c], %[ns]\n\t"
        "s_cselect_b32 %[hi], %[m], %[hi]\n\t"
        "s_cselect_b32 %[lo], %[lo], %[m]\n\t"
        "s_cmp_lg_i32 %[c], %[ns]\n\t"
        "s_cbranch_scc1 Lbs%=\n\t"
        "Ldone%=:\n\t"
        : [q0] "=&s"(q0), [q1] "=&s"(q1), [lo] "=&s"(lo), [hi] "=&s"(hi),
          [m] "=&s"(m), [c] "=&s"(c), [c2] "=&s"(c2), [ns] "=&s"(ns),
          [d] "=&s"(d), [t1] "=&s"(t1), [t2] "=&s"(t2)
        : [k0] "v"(k0), [k1] "v"(k1), [nv] "v"(n)
        : "scc");
      m0 = q0; m1 = q1;
    }
    if (lane == 0) {
      const int r = wave * 8 + rr;
      lds_m[r][0] = (uint32_t)m0;
      lds_m[r][1] = (uint32_t)(m0 >> 32);
      lds_m[r][2] = (uint32_t)m1;
      lds_m[r][3] = (uint32_t)(m1 >> 32);
    }
    k0 = k0n; k1 = k1n; n = nn;
  }
#undef PROBE_UPDATE_EXIT
#undef INTERP_MID

  __syncthreads();
  // bit-transpose: thread (p, t) gathers bit t of rows p*16..p*16+15
  const int p  = threadIdx.x >> 7;
  const int t  = threadIdx.x & 127;
  const int wi = t >> 5, bit = t & 31;
  uint32_t part = 0;
#pragma unroll
  for (int j = 0; j < 16; ++j)
    part |= ((lds_m[p * 16 + j][wi] >> bit) & 1u) << (p * 16 + j);
  lds_p[p][t] = part;
  __syncthreads();
  if (threadIdx.x < 128) {
    const int o = blockIdx.x >> 5;
    const int g = (blockIdx.x >> 2) & 7;
    const int e = blockIdx.x & 3;
    wp[(size_t)(((o * 8 + g) * 4 + e) * 128) + t] = lds_p[0][t] | lds_p[1][t];
  }
}

// K3: out[b][o][t] = popc-dot over 1024 d's (32 words) / 128.  Exact ints.
// wp layout: wp[((o*8+g)*4 + e)*128 + t]  (4 dword loads, stride 512B).
__global__ void popc_gemm(const uint32_t* __restrict__ wp, const uint4* __restrict__ xp,
                          float* __restrict__ out) {
  const int t     = threadIdx.x & 127;
  const int oi    = threadIdx.x >> 7;
  const int opair = blockIdx.x >> 3;
  const int btile = blockIdx.x & 7;
  const int o     = opair * 2 + oi;

  uint4 w[8];
#pragma unroll
  for (int g = 0; g < 8; ++g) {
    const uint32_t* wpw = wp + (size_t)((o * 8 + g) * 4) * 128 + t;
    w[g].x = wpw[0];
    w[g].y = wpw[128];
    w[g].z = wpw[256];
    w[g].w = wpw[384];
  }

#pragma unroll
  for (int ib = 0; ib < 8; ++ib) {
    const int b = btile * 8 + ib;
    uint32_t acc = 0;
#pragma unroll
    for (int g = 0; g < 8; ++g) {
      const uint4 xv = xp[(b * 8 + g) * N_ + t];
      acc += __popc(w[g].x & xv.x);
      acc += __popc(w[g].y & xv.y);
      acc += __popc(w[g].z & xv.z);
      acc += __popc(w[g].w & xv.w);
    }
    out[((size_t)(b * O_) + o) * N_ + t] = (float)acc * (1.0f / 128.0f);
  }
}

extern "C" void kernel_launch(void* const* d_in, const int* in_sizes, int n_in,
                              void* d_out, int out_size, void* d_ws, size_t ws_size,
                              hipStream_t stream) {
  const int*   x    = (const int*)d_in[0];     // (64,1024,128) int32 0/1
  const float* kern = (const float*)d_in[1];   // (512,1024) float32
  float*       out  = (float*)d_out;           // (64,512,128) float32

  char* ws = (char*)d_ws;
  uint32_t* xp = (uint32_t*)ws;                    // 1 MB
  uint32_t* wp = (uint32_t*)(ws + (1u << 20));     // 8 MB

  hipLaunchKernelGGL(pack_x,      dim3(2048),  dim3(128), 0, stream, x, xp);
  hipLaunchKernelGGL(gen_weights, dim3(16384), dim3(256), 0, stream, kern, wp);
  hipLaunchKernelGGL(popc_gemm,   dim3(2048),  dim3(256), 0, stream,
                     wp, (const uint4*)xp, out);
}

// Round 18
// 175.874 us; speedup vs baseline: 1.1830x; 1.0024x over previous
//
#include <hip/hip_runtime.h>
#include <stdint.h>

#define B_ 64
#define D_ 1024
#define O_ 512
#define N_ 128
// rows = O_*D_ = 524288 weight bitstream rows, each of length N_=128

__device__ __forceinline__ uint32_t rotl32(uint32_t x, uint32_t d) {
  // v_alignbit_b32: ((x:x) >> (32-d)) == rotl(x, d) — single VALU inst.
  return __builtin_amdgcn_alignbit(x, x, 32u - d);
}

// Threefry-2x32, 20 rounds, key fixed to jax.random.key(42) -> (0, 42).
__device__ __forceinline__ void threefry2x32(uint32_t c0, uint32_t c1,
                                             uint32_t& r0, uint32_t& r1) {
  const uint32_t ks0 = 0u;
  const uint32_t ks1 = 42u;
  const uint32_t ks2 = 0u ^ 42u ^ 0x1BD11BDAu;
  uint32_t x0 = c0 + ks0;
  uint32_t x1 = c1 + ks1;
#define RND(R) { x0 += x1; x1 = rotl32(x1, R); x1 ^= x0; }
  RND(13) RND(15) RND(26) RND(6)
  x0 += ks1; x1 += ks2 + 1u;
  RND(17) RND(29) RND(16) RND(24)
  x0 += ks2; x1 += ks0 + 2u;
  RND(13) RND(15) RND(26) RND(6)
  x0 += ks0; x1 += ks1 + 3u;
  RND(17) RND(29) RND(16) RND(24)
  x0 += ks1; x1 += ks2 + 4u;
  RND(13) RND(15) RND(26) RND(6)
  x0 += ks2; x1 += ks0 + 5u;
#undef RND
  r0 = x0; r1 = x1;
}

// 32-bit random draw for flat index i, jax_threefry_partitionable semantics:
// counter = (hi32(i)=0, lo32(i)=i), output = out0 ^ out1.
__device__ __forceinline__ uint32_t rand_bits(uint32_t i) {
  uint32_t a, b;
  threefry2x32(0u, i, a, b);
  return a ^ b;
}

// K1: pack input bits along d.  xp[(b*8+g)*128 + t] is a uint4; component e,
// bit j  <->  x[b][d][t] with d = g*128 + e*32 + j.
__global__ void pack_x(const int* __restrict__ x, uint32_t* __restrict__ xp) {
  const int t   = threadIdx.x;            // 0..127
  const int idx = blockIdx.x;             // b*32 + g*4 + e
  const int b   = idx >> 5;
  const int g   = (idx >> 2) & 7;
  const int e   = idx & 3;
  const int* src = x + ((b * D_) + (g * 128 + e * 32)) * N_ + t;
  uint32_t w = 0;
#pragma unroll
  for (int j = 0; j < 32; ++j)
    w |= (uint32_t)(src[j * N_] & 1) << j;
  xp[(((b * 8) + g) * N_ + t) * 4 + e] = w;
}

// K2 (FUSED gen_weights + pack_w): per (o,d) row, reproduce the weight
// bitstream exactly, then transpose in-block to the d-packed GEMM layout.
//
// Row->mask: lane holds keys for t=lane and t=lane+64.
// key = ((rand>>2)&0xFFFFFF80) | t  (monotone in u, stable tie-break by t,
// all 128 keys distinct).  The n smallest keys get bit 1,
// n = round_half_even(clip(p,0,1)*128).
// Selection: interpolation search (4 probes) + verified bisection fallback;
// exit ONLY on count(<m)==n (unique mask); width-1 theorem guarantees
// termination (R9/R14 verified; asm macros byte-identical to R14 + one
// extra interp probe).
//
// Fusion layout math: block = 32 consecutive rows = one o (row/1024 const),
// 32 consecutive d's [d0, d0+32), d0 = (blk%32)*32 -> one (g,e) word-column:
// o = blk>>5, g = (blk>>2)&7, e = blk&3.  Each row's 4 mask words go to
// LDS; after a barrier, 256 threads bit-transpose: thread (p=tid>>7,
// t=tid&127) gathers rows p*16..p*16+15 bit t, halves merged via LDS, and
// wp word (o,g,e,t) stored t-contiguous (coalesced).
// wp layout: wp[((o*8+g)*4 + e)*128 + t].
__global__ void gen_weights(const float* __restrict__ kern, uint32_t* __restrict__ wp) {
  __shared__ uint32_t lds_m[32][4];
  __shared__ uint32_t lds_p[2][128];

  const int lane = threadIdx.x & 63;
  const int wave = threadIdx.x >> 6;
  const int row0 = blockIdx.x * 32 + wave * 8;
  const uint32_t lane2 = (uint32_t)lane + 64u;
  const uint32_t KMASK = 0xFFFFFF80u;
  const uint32_t base_i = (uint32_t)row0 * 128u + (uint32_t)lane;

  // prologue: keys + n for row 0 (software pipeline)
  uint32_t k0 = ((rand_bits(base_i) >> 2) & KMASK) | (uint32_t)lane;
  uint32_t k1 = ((rand_bits(base_i + 64u) >> 2) & KMASK) | lane2;
  float p0 = fminf(fmaxf(kern[row0], 0.0f), 1.0f);
  int n = (int)rintf(p0 * 128.0f);        // RNE, matches jnp.round; uniform

#define PROBE_UPDATE_EXIT                                          \
      "v_cmp_lt_u32 %[q0], %[k0], %[m]\n\t"                        \
      "v_cmp_lt_u32 %[q1], %[k1], %[m]\n\t"                        \
      "s_bcnt1_i32_b64 %[c], %[q0]\n\t"                            \
      "s_bcnt1_i32_b64 %[c2], %[q1]\n\t"                           \
      "s_add_i32 %[c], %[c], %[c2]\n\t"                            \
      "s_cmp_ge_i32 %[c], %[ns]\n\t"                               \
      "s_cselect_b32 %[hi], %[m], %[hi]\n\t"                       \
      "s_cselect_b32 %[lo], %[lo], %[m]\n\t"                       \
      "s_cmp_eq_i32 %[c], %[ns]\n\t"                               \
      "s_cbranch_scc1 Ldone%=\n\t"
#define INTERP_MID                                                 \
      "s_sub_i32 %[d], %[ns], %[c]\n\t"                            \
      "s_lshl_b32 %[d], %[d], 23\n\t"                              \
      "s_add_u32 %[m], %[m], %[d]\n\t"                             \
      "s_add_u32 %[t1], %[lo], 1\n\t"                              \
      "s_add_u32 %[t2], %[hi], -1\n\t"                             \
      "s_min_u32 %[m], %[m], %[t2]\n\t"                            \
      "s_max_u32 %[m], %[m], %[t1]\n\t"

#pragma unroll
  for (int rr = 0; rr < 8; ++rr) {
    // issue next row's independent work first (fills VALU around the asm)
    uint32_t k0n = 0, k1n = 0; int nn = 0;
    if (rr < 7) {
      const uint32_t i0 = base_i + (uint32_t)((rr + 1) * 128);
      k0n = ((rand_bits(i0) >> 2) & KMASK) | (uint32_t)lane;
      k1n = ((rand_bits(i0 + 64u) >> 2) & KMASK) | lane2;
      float p = fminf(fmaxf(kern[row0 + rr + 1], 0.0f), 1.0f);
      nn = (int)rintf(p * 128.0f);
    }

    uint64_t m0, m1;
    if (n <= 0) {                 // uniform condition (verified path)
      m0 = 0ull; m1 = 0ull;
    } else if (n >= 128) {
      m0 = ~0ull; m1 = ~0ull;
    } else {
      uint64_t q0, q1;
      uint32_t lo, hi, m, c, c2, ns, d, t1, t2;
      asm volatile(
        "v_readfirstlane_b32 %[ns], %[nv]\n\t"   // n -> SGPR, guaranteed
        "s_mov_b32 %[lo], 0\n\t"
        "s_mov_b32 %[hi], 0x40000000\n\t"        // 2^30 (keys are 30-bit)
        // ---- interp probe 1: m = n<<23 (interior for n in [1,127]) ----
        "s_lshl_b32 %[m], %[ns], 23\n\t"
        PROBE_UPDATE_EXIT
        // ---- interp probe 2 ----
        INTERP_MID
        PROBE_UPDATE_EXIT
        // ---- interp probe 3 ----
        INTERP_MID
        PROBE_UPDATE_EXIT
        // ---- interp probe 4 ----
        INTERP_MID
        PROBE_UPDATE_EXIT
        // ---- verified bisection, width-1 -> m=hi exact exit ----
        "Lbs%=:\n\t"
        "s_add_u32 %[m], %[lo], %[hi]\n\t"
        "s_lshr_b32 %[m], %[m], 1\n\t"
        "s_add_u32 %[t1], %[lo], 1\n\t"
        "s_max_u32 %[m], %[m], %[t1]\n\t"
        "v_cmp_lt_u32 %[q0], %[k0], %[m]\n\t"
        "v_cmp_lt_u32 %[q1], %[k1], %[m]\n\t"
        "s_bcnt1_i32_b64 %[c], %[q0]\n\t"
        "s_bcnt1_i32_b64 %[c2], %[q1]\n\t"
        "s_add_i32 %[c], %[c], %[c2]\n\t"
        "s_cmp_ge_i32 %[c], %[ns]\n\t"
        "s_cselect_b32 %[hi], %[m], %[hi]\n\t"
        "s_cselect_b32 %[lo], %[lo], %[m]\n\t"
        "s_cmp_lg_i32 %[c], %[ns]\n\t"
        "s_cbranch_scc1 Lbs%=\n\t"
        "Ldone%=:\n\t"
        : [q0] "=&s"(q0), [q1] "=&s"(q1), [lo] "=&s"(lo), [hi] "=&s"(hi),
          [m] "=&s"(m), [c] "=&s"(c), [c2] "=&s"(c2), [ns] "=&s"(ns),
          [d] "=&s"(d), [t1] "=&s"(t1), [t2] "=&s"(t2)
        : [k0] "v"(k0), [k1] "v"(k1), [nv] "v"(n)
        : "scc");
      m0 = q0; m1 = q1;
    }
    if (lane == 0) {
      const int r = wave * 8 + rr;
      lds_m[r][0] = (uint32_t)m0;
      lds_m[r][1] = (uint32_t)(m0 >> 32);
      lds_m[r][2] = (uint32_t)m1;
      lds_m[r][3] = (uint32_t)(m1 >> 32);
    }
    k0 = k0n; k1 = k1n; n = nn;
  }
#undef PROBE_UPDATE_EXIT
#undef INTERP_MID

  __syncthreads();
  // bit-transpose: thread (p, t) gathers bit t of rows p*16..p*16+15
  const int p  = threadIdx.x >> 7;
  const int t  = threadIdx.x & 127;
  const int wi = t >> 5, bit = t & 31;
  uint32_t part = 0;
#pragma unroll
  for (int j = 0; j < 16; ++j)
    part |= ((lds_m[p * 16 + j][wi] >> bit) & 1u) << (p * 16 + j);
  lds_p[p][t] = part;
  __syncthreads();
  if (threadIdx.x < 128) {
    const int o = blockIdx.x >> 5;
    const int g = (blockIdx.x >> 2) & 7;
    const int e = blockIdx.x & 3;
    wp[(size_t)(((o * 8 + g) * 4 + e) * 128) + t] = lds_p[0][t] | lds_p[1][t];
  }
}

// K3: out[b][o][t] = popc-dot over 1024 d's (32 words) / 128.  Exact ints.
// wp layout: wp[((o*8+g)*4 + e)*128 + t]  (4 dword loads, stride 512B).
__global__ void popc_gemm(const uint32_t* __restrict__ wp, const uint4* __restrict__ xp,
                          float* __restrict__ out) {
  const int t     = threadIdx.x & 127;
  const int oi    = threadIdx.x >> 7;
  const int opair = blockIdx.x >> 3;
  const int btile = blockIdx.x & 7;
  const int o     = opair * 2 + oi;

  uint4 w[8];
#pragma unroll
  for (int g = 0; g < 8; ++g) {
    const uint32_t* wpw = wp + (size_t)((o * 8 + g) * 4) * 128 + t;
    w[g].x = wpw[0];
    w[g].y = wpw[128];
    w[g].z = wpw[256];
    w[g].w = wpw[384];
  }

#pragma unroll
  for (int ib = 0; ib < 8; ++ib) {
    const int b = btile * 8 + ib;
    uint32_t acc = 0;
#pragma unroll
    for (int g = 0; g < 8; ++g) {
      const uint4 xv = xp[(b * 8 + g) * N_ + t];
      acc += __popc(w[g].x & xv.x);
      acc += __popc(w[g].y & xv.y);
      acc += __popc(w[g].z & xv.z);
      acc += __popc(w[g].w & xv.w);
    }
    out[((size_t)(b * O_) + o) * N_ + t] = (float)acc * (1.0f / 128.0f);
  }
}

extern "C" void kernel_launch(void* const* d_in, const int* in_sizes, int n_in,
                              void* d_out, int out_size, void* d_ws, size_t ws_size,
                              hipStream_t stream) {
  const int*   x    = (const int*)d_in[0];     // (64,1024,128) int32 0/1
  const float* kern = (const float*)d_in[1];   // (512,1024) float32
  float*       out  = (float*)d_out;           // (64,512,128) float32

  char* ws = (char*)d_ws;
  uint32_t* xp = (uint32_t*)ws;                    // 1 MB
  uint32_t* wp = (uint32_t*)(ws + (1u << 20));     // 8 MB

  hipLaunchKernelGGL(pack_x,      dim3(2048),  dim3(128), 0, stream, x, xp);
  hipLaunchKernelGGL(gen_weights, dim3(16384), dim3(256), 0, stream, kern, wp);
  hipLaunchKernelGGL(popc_gemm,   dim3(2048),  dim3(256), 0, stream,
                     wp, (const uint4*)xp, out);
}